// Round 6
// baseline (117.827 us; speedup 1.0000x reference)
//
#include <hip/hip_runtime.h>

#define NPIX 65536

// ---------------- ws layout (float offsets, plane-granular) ----------------
#define OX1ARE(c) ((0  + (c))*NPIX)
#define OX1AIM(c) ((3  + (c))*NPIX)
#define OX1K(k)   ((6  + (k))*NPIX)
#define OX2ARE(c) ((16 + (c))*NPIX)
#define OX2AIM(c) ((19 + (c))*NPIX)
#define OX2K(k)   ((22 + (k))*NPIX)
#define OX3RE(j)  ((32 + (j))*NPIX)
#define OX3IM(j)  ((37 + (j))*NPIX)
#define OU(k)     ((42 + (k))*NPIX)     // growth-transformed g_k planes
#define OROWS     (52*NPIX)             // 10*256 per-(k,row) kernel sums

// ---------------- FFT machinery (unchanged, proven) ----------------
__device__ __forceinline__ void fft256_core(float* __restrict__ re, float* __restrict__ im,
                                            const float* __restrict__ twr,
                                            const float* __restrict__ twi, int lane) {
    #pragma unroll
    for (int s = 1; s <= 8; ++s) {
        int h = 1 << (s - 1);
        #pragma unroll
        for (int b = 0; b < 2; ++b) {
            int idx = b*64 + lane;
            int pos = idx & (h - 1);
            int g   = idx >> (s - 1);
            int i0 = (g << s) + pos;
            int i1 = i0 + h;
            int tj = pos << (8 - s);
            float wr = twr[tj], wi = twi[tj];
            float xr = re[i1], xi = im[i1];
            float br = fmaf(xr, wr, -xi*wi);
            float bi = fmaf(xr, wi,  xi*wr);
            float ar = re[i0], ai = im[i0];
            re[i0] = ar + br; im[i0] = ai + bi;
            re[i1] = ar - br; im[i1] = ai - bi;
        }
    }
}

__device__ __forceinline__ void build_tw(float* twr, float* twi, int t, float sgn) {
    if (t < 128) {
        float ang = (float)t * 0.0245436930f;   // 2*pi/256
        twr[t] = cosf(ang);
        twi[t] = sgn * sinf(ang);               // -1 forward, +1 inverse
    }
}

__device__ __forceinline__ void store_t4(float* __restrict__ dst, const float* __restrict__ buf,
                                         int off, int t, int lb) {
    float4 v;
    v.x = buf[0*512 + off + t];
    v.y = buf[1*512 + off + t];
    v.z = buf[2*512 + off + t];
    v.w = buf[3*512 + off + t];
    *(float4*)&dst[t*256 + lb] = v;
}

// ---------------- on-the-fly kernel-plane evaluation ----------------
struct KP { float rden, a0,a1,a2, b0,b1,b2, iw0,iw1,iw2; };

__device__ __forceinline__ void load_kp(KP& kp, int k, float R,
        const float* __restrict__ r_, const float* __restrict__ a_,
        const float* __restrict__ b_, const float* __restrict__ w_) {
    kp.rden = 1.0f / ((R + 15.0f) * r_[k]);
    kp.a0 = a_[k*3+0]; kp.a1 = a_[k*3+1]; kp.a2 = a_[k*3+2];
    kp.b0 = b_[k*3+0]; kp.b1 = b_[k*3+1]; kp.b2 = b_[k*3+2];
    kp.iw0 = 1.0f/w_[k*3+0]; kp.iw1 = 1.0f/w_[k*3+1]; kp.iw2 = 1.0f/w_[k*3+2];
}

__device__ __forceinline__ float kval(int di, int dj, const KP& kp) {
    float D  = sqrtf((float)(di*di + dj*dj));
    float Dk = D * kp.rden;
    if (Dk > 3.0f) return 0.0f;     // contribution < 1e-12
    float d0 = Dk - kp.a0, d1 = Dk - kp.a1, d2 = Dk - kp.a2;
    float ker = kp.b0*expf(-(d0*d0)*kp.iw0)
              + kp.b1*expf(-(d1*d1)*kp.iw1)
              + kp.b2*expf(-(d2*d2)*kp.iw2);
    float sig = 1.0f / (1.0f + expf(10.0f*(Dk - 1.0f)));
    return sig * ker;
}

// ---------------- pass 1: forward row FFTs ----------------
__global__ __launch_bounds__(256) void fwd_rows(const float* __restrict__ A,
        const float* __restrict__ R_, const float* __restrict__ r_,
        const float* __restrict__ a_, const float* __restrict__ b_,
        const float* __restrict__ w_, float* __restrict__ ws) {
    __shared__ float buf[4*512];
    __shared__ float twr[128], twi[128];
    int p  = blockIdx.x >> 6;
    int lb = (blockIdx.x & 63) * 4;
    int wid = threadIdx.x >> 6, lane = threadIdx.x & 63;
    int t = threadIdx.x;
    build_tw(twr, twi, t, -1.0f);
    int iw = lb + wid;                 // natural row for A, wrapped row for K
    float* re = &buf[wid*512];
    float* im = re + 256;

    int fa, fb;                        // plane ids: 0..2 = A ch, 3..12 = K0..K9
    switch (p) {
        case 0:  fa = 0;  fb = 1;  break;
        case 1:  fa = 2;  fb = 12; break;
        case 2:  fa = 3;  fb = 4;  break;
        case 3:  fa = 5;  fb = 6;  break;
        case 4:  fa = 7;  fb = 8;  break;
        case 5:  fa = 9;  fb = 10; break;
        default: fa = 11; fb = -1; break;
    }
    bool aA = (fa < 3);
    bool bA = (fb >= 0 && fb < 3);
    float R = R_[0];
    int di = ((iw + 128) & 255) - 128;
    KP kpa, kpb;
    if (!aA)      load_kp(kpa, fa - 3, R, r_, a_, b_, w_);
    if (fb >= 3)  load_kp(kpb, fb - 3, R, r_, a_, b_, w_);
    float sum_a = 0.0f, sum_b = 0.0f;
    #pragma unroll
    for (int e = 0; e < 4; ++e) {
        int idx = e*64 + lane;
        int dst = __brev(idx) >> 24;
        int dj  = ((idx + 128) & 255) - 128;
        float vf, vg;
        if (aA) vf = A[(iw*256 + idx)*3 + fa];
        else    { vf = kval(di, dj, kpa); sum_a += vf; }
        if (fb < 0)      vg = 0.0f;
        else if (bA)     vg = A[(iw*256 + idx)*3 + fb];
        else             { vg = kval(di, dj, kpb); sum_b += vg; }
        re[dst] = vf;
        im[dst] = vg;
    }
    if (!aA) {
        float s = sum_a;
        #pragma unroll
        for (int off = 32; off; off >>= 1) s += __shfl_xor(s, off);
        if (lane == 0) ws[OROWS + (fa - 3)*256 + iw] = s;
    }
    if (fb >= 3) {
        float s = sum_b;
        #pragma unroll
        for (int off = 32; off; off >>= 1) s += __shfl_xor(s, off);
        if (lane == 0) ws[OROWS + (fb - 3)*256 + iw] = s;
    }
    __syncthreads();
    fft256_core(re, im, twr, twi, lane);
    __syncthreads();
    if (t <= 128) {                        // Hermitian: only u<=128 needed
        if (p <= 1) {
            int u2 = (256 - t) & 255;
            float4 Fre, Fim, Gre, Gim;
            float* pF[4] = {&Fre.x, &Fim.x, &Gre.x, &Gim.x};
            #pragma unroll
            for (int l = 0; l < 4; ++l) {
                float zr1 = buf[l*512 + t],  zi1 = buf[l*512 + 256 + t];
                float zr2 = buf[l*512 + u2], zi2 = buf[l*512 + 256 + u2];
                pF[0][l] = 0.5f*(zr1 + zr2);
                pF[1][l] = 0.5f*(zi1 - zi2);
                pF[2][l] = 0.5f*(zi1 + zi2);
                pF[3][l] = 0.5f*(zr2 - zr1);
            }
            if (p == 0) {
                *(float4*)&ws[OX1ARE(0) + t*256 + lb] = Fre;
                *(float4*)&ws[OX1AIM(0) + t*256 + lb] = Fim;
                *(float4*)&ws[OX1ARE(1) + t*256 + lb] = Gre;
                *(float4*)&ws[OX1AIM(1) + t*256 + lb] = Gim;
            } else {
                *(float4*)&ws[OX1ARE(2) + t*256 + lb] = Fre;
                *(float4*)&ws[OX1AIM(2) + t*256 + lb] = Fim;
                *(float4*)&ws[OX1K(9)   + t*256 + lb] = Gre;  // K9 spectrum real
            }
        } else {
            // both inputs real+even -> spectra real: F=Re(Z), G=Im(Z)
            float4 va, vb;
            float* pV[2] = {&va.x, &vb.x};
            #pragma unroll
            for (int l = 0; l < 4; ++l) {
                pV[0][l] = buf[l*512 + t];
                pV[1][l] = buf[l*512 + 256 + t];
            }
            *(float4*)&ws[OX1K(fa - 3) + t*256 + lb] = va;
            if (fb >= 0) *(float4*)&ws[OX1K(fb - 3) + t*256 + lb] = vb;
        }
    }
}

// ---------------- pass 2: forward column FFTs, u-rows 0..128 only ----------------
__global__ __launch_bounds__(256) void fwd_cols(float* __restrict__ ws) {
    __shared__ float buf[4*512];
    __shared__ float twr[128], twi[128];
    __shared__ float kks[2];
    int bid = blockIdx.x;
    int wid = threadIdx.x >> 6, lane = threadIdx.x & 63;
    int t = threadIdx.x;
    build_tw(twr, twi, t, -1.0f);
    float* re = &buf[wid*512];
    float* im = re + 256;
    if (bid < 99) {
        int c  = bid / 33;
        int ub = (bid % 33) * 4;
        int u  = ub + wid; if (u > 128) u = 128;     // dup row 128 into pad cols
        const float* rr = ws + OX1ARE(c) + u*256;
        const float* ri = ws + OX1AIM(c) + u*256;
        #pragma unroll
        for (int e = 0; e < 4; ++e) {
            int idx = e*64 + lane;
            int dst = __brev(idx) >> 24;
            re[dst] = rr[idx];
            im[dst] = ri[idx];
        }
        __syncthreads();
        fft256_core(re, im, twr, twi, lane);
        __syncthreads();
        store_t4(ws + OX2ARE(c), buf, 0,   t, ub);
        store_t4(ws + OX2AIM(c), buf, 256, t, ub);
    } else {
        int q  = (bid - 99) / 33;
        int ub = ((bid - 99) % 33) * 4;
        int u  = ub + wid; if (u > 128) u = 128;
        // per-plane normalization: kinv/65536 from the row sums
        if (wid < 2) {
            const float* rw = ws + OROWS + (2*q + wid)*256;
            float v = rw[lane] + rw[64+lane] + rw[128+lane] + rw[192+lane];
            #pragma unroll
            for (int off = 32; off; off >>= 1) v += __shfl_xor(v, off);
            if (lane == 0) kks[wid] = 1.0f / (v * 65536.0f);
        }
        const float* ra = ws + OX1K(2*q)     + u*256;
        const float* rb = ws + OX1K(2*q + 1) + u*256;
        #pragma unroll
        for (int e = 0; e < 4; ++e) {
            int idx = e*64 + lane;
            int dst = __brev(idx) >> 24;
            re[dst] = ra[idx];
            im[dst] = rb[idx];
        }
        __syncthreads();
        fft256_core(re, im, twr, twi, lane);
        __syncthreads();
        if (t <= 128) {                              // even in v
            float sa = kks[0], sb = kks[1];
            float4 va, vb;
            va.x = buf[0*512 + t]*sa;  vb.x = buf[0*512 + 256 + t]*sb;
            va.y = buf[1*512 + t]*sa;  vb.y = buf[1*512 + 256 + t]*sb;
            va.z = buf[2*512 + t]*sa;  vb.z = buf[2*512 + 256 + t]*sb;
            va.w = buf[3*512 + t]*sa;  vb.w = buf[3*512 + 256 + t]*sb;
            *(float4*)&ws[OX2K(2*q)     + t*256 + ub] = va;
            *(float4*)&ws[OX2K(2*q + 1) + t*256 + ub] = vb;
        }
    }
}

// ---------------- pass 3: U-hat = A-hat * K-hat (K real), inverse row FFT ----
__global__ __launch_bounds__(256) void inv_rows(float* __restrict__ ws) {
    __shared__ float buf[4*512];
    __shared__ float twr[128], twi[128];
    int j  = blockIdx.x >> 6;
    int lb = (blockIdx.x & 63) * 4;
    int wid = threadIdx.x >> 6, lane = threadIdx.x & 63;
    int t = threadIdx.x;
    build_tw(twr, twi, t, 1.0f);
    int ka = 2*j, kb = 2*j + 1;
    int ca = (ka < 9) ? ka/3 : 0;        // C0 = {0,0,0,1,1,1,2,2,2,0}
    int cb = (kb < 9) ? kb/3 : 0;
    int v  = lb + wid;
    int vr = (256 - v) & 255;
    int vf = (v <= 128) ? v : 256 - v;
    const float* Aare_v = ws + OX2ARE(ca) + v*256;
    const float* Aaim_v = ws + OX2AIM(ca) + v*256;
    const float* Aare_r = ws + OX2ARE(ca) + vr*256;
    const float* Aaim_r = ws + OX2AIM(ca) + vr*256;
    const float* Bare_v = ws + OX2ARE(cb) + v*256;
    const float* Baim_v = ws + OX2AIM(cb) + v*256;
    const float* Bare_r = ws + OX2ARE(cb) + vr*256;
    const float* Baim_r = ws + OX2AIM(cb) + vr*256;
    const float* Ka = ws + OX2K(ka) + vf*256;
    const float* Kb = ws + OX2K(kb) + vf*256;
    float* re = &buf[wid*512];
    float* im = re + 256;
    #pragma unroll
    for (int e = 0; e < 4; ++e) {
        int idx = e*64 + lane;
        int dst = __brev(idx) >> 24;
        bool hi = idx > 128;
        int uf = hi ? 256 - idx : idx;
        const float* pAr = hi ? Aare_r : Aare_v;
        const float* pAi = hi ? Aaim_r : Aaim_v;
        const float* pBr = hi ? Bare_r : Bare_v;
        const float* pBi = hi ? Baim_r : Baim_v;
        float ar = pAr[uf];
        float ai = pAi[uf]; ai = hi ? -ai : ai;
        float br = pBr[uf];
        float bi = pBi[uf]; bi = hi ? -bi : bi;
        float kva = Ka[uf], kvb = Kb[uf];
        float uar = ar*kva, uai = ai*kva;     // complex * real
        float ubr = br*kvb, ubi = bi*kvb;
        re[dst] = uar - ubi;                  // Z = Ua + i*Ub
        im[dst] = uai + ubr;
    }
    __syncthreads();
    fft256_core(re, im, twr, twi, lane);
    __syncthreads();
    store_t4(ws + OX3RE(j), buf, 0,   t, lb);
    store_t4(ws + OX3IM(j), buf, 256, t, lb);
}

// ---------------- pass 4: inverse column FFT + growth transform ----------------
__global__ __launch_bounds__(256) void inv_cols(float* __restrict__ ws,
                                                const float* __restrict__ m_,
                                                const float* __restrict__ s_,
                                                const float* __restrict__ h_) {
    __shared__ float buf[4*512];
    __shared__ float twr[128], twi[128];
    int j  = blockIdx.x >> 6;
    int lb = (blockIdx.x & 63) * 4;
    int wid = threadIdx.x >> 6, lane = threadIdx.x & 63;
    int t = threadIdx.x;
    build_tw(twr, twi, t, 1.0f);
    float* re = &buf[wid*512];
    float* im = re + 256;
    const float* rr = ws + OX3RE(j) + (lb + wid)*256;
    const float* ri = ws + OX3IM(j) + (lb + wid)*256;
    #pragma unroll
    for (int e = 0; e < 4; ++e) {
        int idx = e*64 + lane;
        int dst = __brev(idx) >> 24;
        re[dst] = rr[idx];
        im[dst] = ri[idx];
    }
    __syncthreads();
    fft256_core(re, im, twr, twi, lane);
    __syncthreads();
    int k0 = 2*j, k1 = 2*j + 1;
    float m0 = m_[k0], m1 = m_[k1];
    float c0 = 0.5f/(s_[k0]*s_[k0]), c1 = 0.5f/(s_[k1]*s_[k1]);
    float h0 = h_[k0], h1 = h_[k1];
    float4 va, vb;
    #pragma unroll
    for (int l = 0; l < 4; ++l) {
        float u0 = buf[l*512 + t]       - m0;
        float u1 = buf[l*512 + 256 + t] - m1;
        (&va.x)[l] = h0 * fmaf(2.0f, expf(-(u0*u0)*c0), -1.0f);
        (&vb.x)[l] = h1 * fmaf(2.0f, expf(-(u1*u1)*c1), -1.0f);
    }
    *(float4*)&ws[OU(k0) + t*256 + lb] = va;
    *(float4*)&ws[OU(k1) + t*256 + lb] = vb;
}

// ---------------- fused growth-sum + sobel + mu + LDS scatter reintegration ----
// Block (c,x) owns dest row x. It loads G/A-sum rows x-6..x+6 (26.6 KB LDS),
// recomputes mu for source rows x-5..x+5 (redundant across blocks; ~0.4 us
// aggregate VALU), and scatters each source's <=3-wide y-window into a
// 256-float LDS accumulator (proven R5 ds_add pattern). Kills the growth_mu
// dispatch + the OPACK plane round-trip.
__global__ __launch_bounds__(256) void growth_rt(const float* __restrict__ A,
                                                 const float* __restrict__ ws,
                                                 float* __restrict__ out) {
    __shared__ float Gs[13][256];
    __shared__ float As[13][256];
    __shared__ float acc[256];
    int b = blockIdx.x;
    int c = b >> 8;
    int x = b & 255;
    int t = threadIdx.x;
    int nk = (c == 0) ? 4 : 3;
    acc[t] = 0.0f;
    for (int i = 0; i < 13; ++i) {
        int xr = x - 6 + i;
        float sv = 0.0f, gv = 0.0f;
        if (xr >= 0 && xr <= 255) {
            int idx = xr*256 + t;
            int base = idx*3;
            sv = A[base] + A[base + 1] + A[base + 2];
            for (int kk = 0; kk < nk; ++kk) {
                int k = (kk == 3) ? 9 : c*3 + kk;
                gv += ws[OU(k) + idx];
            }
        }
        As[i][t] = sv;
        Gs[i][t] = gv;
    }
    __syncthreads();
    int y = t;
    #pragma unroll
    for (int i = 0; i < 11; ++i) {
        int xr = x - 5 + i;                 // source row (block-uniform branch)
        if (xr < 0 || xr > 255) continue;
        int ri = i + 1;                     // buffer row of xr (x-6 -> 0)
        float vA[3][3], vU[3][3];
        #pragma unroll
        for (int ii = 0; ii < 3; ++ii)
            #pragma unroll
            for (int jj = 0; jj < 3; ++jj) {
                int yy = y - 1 + jj;
                bool ok = (yy >= 0 && yy <= 255);
                vA[ii][jj] = ok ? As[ri - 1 + ii][yy] : 0.0f;
                vU[ii][jj] = ok ? Gs[ri - 1 + ii][yy] : 0.0f;
            }
        float gyA = (vA[0][0] + 2.0f*vA[0][1] + vA[0][2]) - (vA[2][0] + 2.0f*vA[2][1] + vA[2][2]);
        float gxA = (vA[0][0] + 2.0f*vA[1][0] + vA[2][0]) - (vA[0][2] + 2.0f*vA[1][2] + vA[2][2]);
        float gy  = (vU[0][0] + 2.0f*vU[0][1] + vU[0][2]) - (vU[2][0] + 2.0f*vU[2][1] + vU[2][2]);
        float gx  = (vU[0][0] + 2.0f*vU[1][0] + vU[2][0]) - (vU[0][2] + 2.0f*vU[1][2] + vU[2][2]);
        float a = A[(xr*256 + y)*3 + c];
        float al = (a / 3.0f); al = al * al;
        al = fminf(fmaxf(al, 0.0f), 1.0f);
        float F0 = gy * (1.0f - al) - gyA * al;
        float F1 = gx * (1.0f - al) - gxA * al;
        float d0 = fminf(fmaxf(0.2f * F0, -4.35f), 4.35f);
        float d1 = fminf(fmaxf(0.2f * F1, -4.35f), 4.35f);
        float mux = fminf(fmaxf((float)xr + 0.5f + d0, 0.65f), 255.35f);
        float muy = fminf(fmaxf((float)y  + 0.5f + d1, 0.65f), 255.35f);
        float dxp = mux - ((float)xr + 0.5f);      // clamped x-displacement
        float dxf = (float)(x - xr);               // dest-row offset, -5..5
        float wx  = __builtin_amdgcn_fmed3f(1.15f - fabsf(dxf - dxp), 0.0f, 1.0f);
        float wxa = a * wx;
        if (wxa != 0.0f) {
            int by = (int)ceilf(muy - 1.65f);      // first dest y with ay possibly > 0
            float fy = (float)by + 0.5f - muy;
            #pragma unroll
            for (int q = 0; q < 3; ++q) {
                float ay = __builtin_amdgcn_fmed3f(1.15f - fabsf(fy + (float)q), 0.0f, 1.0f);
                atomicAdd(&acc[(by + q) & 255], wxa * ay);   // wrapped slots get ay==0
            }
        }
    }
    __syncthreads();
    out[(x*256 + t)*3 + c] = acc[t] * (1.0f / (4.0f * 0.65f * 0.65f));
}

extern "C" void kernel_launch(void* const* d_in, const int* in_sizes, int n_in,
                              void* d_out, int out_size, void* d_ws, size_t ws_size,
                              hipStream_t stream) {
    const float* A = (const float*)d_in[0];
    const float* R = (const float*)d_in[1];
    const float* r = (const float*)d_in[2];
    const float* m = (const float*)d_in[3];
    const float* s = (const float*)d_in[4];
    const float* h = (const float*)d_in[5];
    const float* a = (const float*)d_in[6];
    const float* b = (const float*)d_in[7];
    const float* w = (const float*)d_in[8];
    float* ws  = (float*)d_ws;
    float* out = (float*)d_out;

    fwd_rows<<<7*64, 256, 0, stream>>>(A, R, r, a, b, w, ws);
    fwd_cols<<<99 + 165, 256, 0, stream>>>(ws);
    inv_rows<<<5*64, 256, 0, stream>>>(ws);
    inv_cols<<<5*64, 256, 0, stream>>>(ws, m, s, h);
    growth_rt<<<768, 256, 0, stream>>>(A, ws, out);
}

// Round 7
// 111.254 us; speedup vs baseline: 1.0591x; 1.0591x over previous
//
#include <hip/hip_runtime.h>

#define NPIX 65536

// ---------------- ws layout (float offsets, plane-granular) ----------------
// X1A: row-spectra of A0..A2 (complex, rows u=0..128 used)
// X1K: row-spectra of K0..K9 (REAL - kernels are even in j, rows u=0..128)
// X2A: full 2D hats of A (complex, all v rows, u cols 0..131 written, <=128 read)
// X2K: 2D hats of K (REAL+even: rows v<=128, cols u<=131 written, <=128 read)
// X3 : pass-3 output [j_spatial][v] (complex, full)
// U  : 10 unnormalized convolution planes
#define OX1ARE(c) ((0  + (c))*NPIX)
#define OX1AIM(c) ((3  + (c))*NPIX)
#define OX1K(k)   ((6  + (k))*NPIX)
#define OX2ARE(c) ((16 + (c))*NPIX)
#define OX2AIM(c) ((19 + (c))*NPIX)
#define OX2K(k)   ((22 + (k))*NPIX)
#define OX3RE(j)  ((32 + (j))*NPIX)
#define OX3IM(j)  ((37 + (j))*NPIX)
#define OU(k)     ((42 + (k))*NPIX)
#define OMUX(c)   ((52 + (c))*NPIX)
#define OMUY(c)   ((55 + (c))*NPIX)
#define OROWS     (58*NPIX)          // 10*256 per-(k,row) kernel sums

// ---------------- FFT machinery ----------------
__device__ __forceinline__ void fft256_core(float* __restrict__ re, float* __restrict__ im,
                                            const float* __restrict__ twr,
                                            const float* __restrict__ twi, int lane) {
    #pragma unroll
    for (int s = 1; s <= 8; ++s) {
        int h = 1 << (s - 1);
        #pragma unroll
        for (int b = 0; b < 2; ++b) {
            int idx = b*64 + lane;
            int pos = idx & (h - 1);
            int g   = idx >> (s - 1);
            int i0 = (g << s) + pos;
            int i1 = i0 + h;
            int tj = pos << (8 - s);
            float wr = twr[tj], wi = twi[tj];
            float xr = re[i1], xi = im[i1];
            float br = fmaf(xr, wr, -xi*wi);
            float bi = fmaf(xr, wi,  xi*wr);
            float ar = re[i0], ai = im[i0];
            re[i0] = ar + br; im[i0] = ai + bi;
            re[i1] = ar - br; im[i1] = ai - bi;
        }
    }
}

__device__ __forceinline__ void build_tw(float* twr, float* twi, int t, float sgn) {
    if (t < 128) {
        float ang = (float)t * 0.0245436930f;   // 2*pi/256
        twr[t] = cosf(ang);
        twi[t] = sgn * sinf(ang);               // -1 forward, +1 inverse
    }
}

__device__ __forceinline__ void store_t4(float* __restrict__ dst, const float* __restrict__ buf,
                                         int off, int t, int lb) {
    float4 v;
    v.x = buf[0*512 + off + t];
    v.y = buf[1*512 + off + t];
    v.z = buf[2*512 + off + t];
    v.w = buf[3*512 + off + t];
    *(float4*)&dst[t*256 + lb] = v;
}

// ---------------- on-the-fly kernel-plane evaluation ----------------
struct KP { float rden, a0,a1,a2, b0,b1,b2, iw0,iw1,iw2; };

__device__ __forceinline__ void load_kp(KP& kp, int k, float R,
        const float* __restrict__ r_, const float* __restrict__ a_,
        const float* __restrict__ b_, const float* __restrict__ w_) {
    kp.rden = 1.0f / ((R + 15.0f) * r_[k]);
    kp.a0 = a_[k*3+0]; kp.a1 = a_[k*3+1]; kp.a2 = a_[k*3+2];
    kp.b0 = b_[k*3+0]; kp.b1 = b_[k*3+1]; kp.b2 = b_[k*3+2];
    kp.iw0 = 1.0f/w_[k*3+0]; kp.iw1 = 1.0f/w_[k*3+1]; kp.iw2 = 1.0f/w_[k*3+2];
}

__device__ __forceinline__ float kval(int di, int dj, const KP& kp) {
    float D  = sqrtf((float)(di*di + dj*dj));
    float Dk = D * kp.rden;
    // beyond Dk=3 contribution < 1e-12 -> skip transcendentals
    if (Dk > 3.0f) return 0.0f;
    float d0 = Dk - kp.a0, d1 = Dk - kp.a1, d2 = Dk - kp.a2;
    float ker = kp.b0*expf(-(d0*d0)*kp.iw0)
              + kp.b1*expf(-(d1*d1)*kp.iw1)
              + kp.b2*expf(-(d2*d2)*kp.iw2);
    float sig = 1.0f / (1.0f + expf(10.0f*(Dk - 1.0f)));   // == 0.5*(tanh(-5(Dk-1))+1)
    return sig * ker;
}

// ---------------- pass 1: forward row FFTs ----------------
__global__ __launch_bounds__(256) void fwd_rows(const float* __restrict__ A,
        const float* __restrict__ R_, const float* __restrict__ r_,
        const float* __restrict__ a_, const float* __restrict__ b_,
        const float* __restrict__ w_, float* __restrict__ ws) {
    __shared__ float buf[4*512];
    __shared__ float twr[128], twi[128];
    int p  = blockIdx.x >> 6;
    int lb = (blockIdx.x & 63) * 4;
    int wid = threadIdx.x >> 6, lane = threadIdx.x & 63;
    int t = threadIdx.x;
    build_tw(twr, twi, t, -1.0f);
    int iw = lb + wid;                 // natural row for A, wrapped row for K
    float* re = &buf[wid*512];
    float* im = re + 256;

    int fa, fb;                        // plane ids: 0..2 = A ch, 3..12 = K0..K9
    switch (p) {
        case 0:  fa = 0;  fb = 1;  break;
        case 1:  fa = 2;  fb = 12; break;
        case 2:  fa = 3;  fb = 4;  break;
        case 3:  fa = 5;  fb = 6;  break;
        case 4:  fa = 7;  fb = 8;  break;
        case 5:  fa = 9;  fb = 10; break;
        default: fa = 11; fb = -1; break;
    }
    bool aA = (fa < 3);
    bool bA = (fb >= 0 && fb < 3);
    float R = R_[0];
    int di = ((iw + 128) & 255) - 128;
    KP kpa, kpb;
    if (!aA)      load_kp(kpa, fa - 3, R, r_, a_, b_, w_);
    if (fb >= 3)  load_kp(kpb, fb - 3, R, r_, a_, b_, w_);
    float sum_a = 0.0f, sum_b = 0.0f;
    #pragma unroll
    for (int e = 0; e < 4; ++e) {
        int idx = e*64 + lane;
        int dst = __brev(idx) >> 24;
        int dj  = ((idx + 128) & 255) - 128;
        float vf, vg;
        if (aA) vf = A[(iw*256 + idx)*3 + fa];
        else    { vf = kval(di, dj, kpa); sum_a += vf; }
        if (fb < 0)      vg = 0.0f;
        else if (bA)     vg = A[(iw*256 + idx)*3 + fb];
        else             { vg = kval(di, dj, kpb); sum_b += vg; }
        re[dst] = vf;
        im[dst] = vg;
    }
    if (!aA) {
        float s = sum_a;
        #pragma unroll
        for (int off = 32; off; off >>= 1) s += __shfl_xor(s, off);
        if (lane == 0) ws[OROWS + (fa - 3)*256 + iw] = s;
    }
    if (fb >= 3) {
        float s = sum_b;
        #pragma unroll
        for (int off = 32; off; off >>= 1) s += __shfl_xor(s, off);
        if (lane == 0) ws[OROWS + (fb - 3)*256 + iw] = s;
    }
    __syncthreads();
    fft256_core(re, im, twr, twi, lane);
    __syncthreads();
    if (t <= 128) {                        // Hermitian: only u<=128 needed
        if (p <= 1) {
            int u2 = (256 - t) & 255;
            float4 Fre, Fim, Gre, Gim;
            float* pF[4] = {&Fre.x, &Fim.x, &Gre.x, &Gim.x};
            #pragma unroll
            for (int l = 0; l < 4; ++l) {
                float zr1 = buf[l*512 + t],  zi1 = buf[l*512 + 256 + t];
                float zr2 = buf[l*512 + u2], zi2 = buf[l*512 + 256 + u2];
                pF[0][l] = 0.5f*(zr1 + zr2);
                pF[1][l] = 0.5f*(zi1 - zi2);
                pF[2][l] = 0.5f*(zi1 + zi2);
                pF[3][l] = 0.5f*(zr2 - zr1);
            }
            if (p == 0) {
                *(float4*)&ws[OX1ARE(0) + t*256 + lb] = Fre;
                *(float4*)&ws[OX1AIM(0) + t*256 + lb] = Fim;
                *(float4*)&ws[OX1ARE(1) + t*256 + lb] = Gre;
                *(float4*)&ws[OX1AIM(1) + t*256 + lb] = Gim;
            } else {
                *(float4*)&ws[OX1ARE(2) + t*256 + lb] = Fre;
                *(float4*)&ws[OX1AIM(2) + t*256 + lb] = Fim;
                *(float4*)&ws[OX1K(9)   + t*256 + lb] = Gre;  // K9 spectrum real
            }
        } else {
            // both inputs real+even -> spectra real: F=Re(Z), G=Im(Z)
            float4 va, vb;
            float* pV[2] = {&va.x, &vb.x};
            #pragma unroll
            for (int l = 0; l < 4; ++l) {
                pV[0][l] = buf[l*512 + t];
                pV[1][l] = buf[l*512 + 256 + t];
            }
            *(float4*)&ws[OX1K(fa - 3) + t*256 + lb] = va;
            if (fb >= 0) *(float4*)&ws[OX1K(fb - 3) + t*256 + lb] = vb;
        }
    }
}

// ---------------- pass 2: forward column FFTs, u-rows 0..128 only ----------------
__global__ __launch_bounds__(256) void fwd_cols(float* __restrict__ ws) {
    __shared__ float buf[4*512];
    __shared__ float twr[128], twi[128];
    int bid = blockIdx.x;
    int wid = threadIdx.x >> 6, lane = threadIdx.x & 63;
    int t = threadIdx.x;
    build_tw(twr, twi, t, -1.0f);
    float* re = &buf[wid*512];
    float* im = re + 256;
    if (bid < 99) {
        int c  = bid / 33;
        int ub = (bid % 33) * 4;
        int u  = ub + wid; if (u > 128) u = 128;     // dup row 128 into pad cols
        const float* rr = ws + OX1ARE(c) + u*256;
        const float* ri = ws + OX1AIM(c) + u*256;
        #pragma unroll
        for (int e = 0; e < 4; ++e) {
            int idx = e*64 + lane;
            int dst = __brev(idx) >> 24;
            re[dst] = rr[idx];
            im[dst] = ri[idx];
        }
        __syncthreads();
        fft256_core(re, im, twr, twi, lane);
        __syncthreads();
        store_t4(ws + OX2ARE(c), buf, 0,   t, ub);
        store_t4(ws + OX2AIM(c), buf, 256, t, ub);
    } else {
        int q  = (bid - 99) / 33;
        int ub = ((bid - 99) % 33) * 4;
        int u  = ub + wid; if (u > 128) u = 128;
        const float* ra = ws + OX1K(2*q)     + u*256;
        const float* rb = ws + OX1K(2*q + 1) + u*256;
        #pragma unroll
        for (int e = 0; e < 4; ++e) {
            int idx = e*64 + lane;
            int dst = __brev(idx) >> 24;
            re[dst] = ra[idx];
            im[dst] = rb[idx];
        }
        __syncthreads();
        fft256_core(re, im, twr, twi, lane);
        __syncthreads();
        if (t <= 128) {                              // even in v
            store_t4(ws + OX2K(2*q),     buf, 0,   t, ub);
            store_t4(ws + OX2K(2*q + 1), buf, 256, t, ub);
        }
    }
}

// ---------------- pass 3: U-hat = A-hat * K-hat (K real), inverse row FFT ----
__global__ __launch_bounds__(256) void inv_rows(float* __restrict__ ws) {
    __shared__ float buf[4*512];
    __shared__ float twr[128], twi[128];
    int j  = blockIdx.x >> 6;
    int lb = (blockIdx.x & 63) * 4;
    int wid = threadIdx.x >> 6, lane = threadIdx.x & 63;
    int t = threadIdx.x;
    build_tw(twr, twi, t, 1.0f);
    int ka = 2*j, kb = 2*j + 1;
    int ca = (ka < 9) ? ka/3 : 0;        // C0 = {0,0,0,1,1,1,2,2,2,0}
    int cb = (kb < 9) ? kb/3 : 0;
    int v  = lb + wid;
    int vr = (256 - v) & 255;
    int vf = (v <= 128) ? v : 256 - v;
    const float* Aare_v = ws + OX2ARE(ca) + v*256;
    const float* Aaim_v = ws + OX2AIM(ca) + v*256;
    const float* Aare_r = ws + OX2ARE(ca) + vr*256;
    const float* Aaim_r = ws + OX2AIM(ca) + vr*256;
    const float* Bare_v = ws + OX2ARE(cb) + v*256;
    const float* Baim_v = ws + OX2AIM(cb) + v*256;
    const float* Bare_r = ws + OX2ARE(cb) + vr*256;
    const float* Baim_r = ws + OX2AIM(cb) + vr*256;
    const float* Ka = ws + OX2K(ka) + vf*256;
    const float* Kb = ws + OX2K(kb) + vf*256;
    float* re = &buf[wid*512];
    float* im = re + 256;
    #pragma unroll
    for (int e = 0; e < 4; ++e) {
        int idx = e*64 + lane;
        int dst = __brev(idx) >> 24;
        bool hi = idx > 128;
        int uf = hi ? 256 - idx : idx;
        const float* pAr = hi ? Aare_r : Aare_v;
        const float* pAi = hi ? Aaim_r : Aaim_v;
        const float* pBr = hi ? Bare_r : Bare_v;
        const float* pBi = hi ? Baim_r : Baim_v;
        float ar = pAr[uf];
        float ai = pAi[uf]; ai = hi ? -ai : ai;
        float br = pBr[uf];
        float bi = pBi[uf]; bi = hi ? -bi : bi;
        float kva = Ka[uf], kvb = Kb[uf];
        float uar = ar*kva, uai = ai*kva;     // complex * real
        float ubr = br*kvb, ubi = bi*kvb;
        re[dst] = uar - ubi;                  // Z = Ua + i*Ub
        im[dst] = uai + ubr;
    }
    __syncthreads();
    fft256_core(re, im, twr, twi, lane);
    __syncthreads();
    store_t4(ws + OX3RE(j), buf, 0,   t, lb);
    store_t4(ws + OX3IM(j), buf, 256, t, lb);
}

// ---------------- pass 4: inverse column FFT; re/65536 -> U2j, im -> U2j+1 ----
__global__ __launch_bounds__(256) void inv_cols(float* __restrict__ ws) {
    __shared__ float buf[4*512];
    __shared__ float twr[128], twi[128];
    int j  = blockIdx.x >> 6;
    int lb = (blockIdx.x & 63) * 4;
    int wid = threadIdx.x >> 6, lane = threadIdx.x & 63;
    int t = threadIdx.x;
    build_tw(twr, twi, t, 1.0f);
    float* re = &buf[wid*512];
    float* im = re + 256;
    const float* rr = ws + OX3RE(j) + (lb + wid)*256;
    const float* ri = ws + OX3IM(j) + (lb + wid)*256;
    #pragma unroll
    for (int e = 0; e < 4; ++e) {
        int idx = e*64 + lane;
        int dst = __brev(idx) >> 24;
        re[dst] = rr[idx];
        im[dst] = ri[idx];
    }
    __syncthreads();
    fft256_core(re, im, twr, twi, lane);
    __syncthreads();
    const float sc = 1.0f / 65536.0f;
    float4 va, vb;
    va.x = buf[0*512 + t] * sc;       vb.x = buf[0*512 + 256 + t] * sc;
    va.y = buf[1*512 + t] * sc;       vb.y = buf[1*512 + 256 + t] * sc;
    va.z = buf[2*512 + t] * sc;       vb.z = buf[2*512 + 256 + t] * sc;
    va.w = buf[3*512 + t] * sc;       vb.w = buf[3*512 + 256 + t] * sc;
    *(float4*)&ws[OU(2*j)     + t*256 + lb] = va;
    *(float4*)&ws[OU(2*j + 1) + t*256 + lb] = vb;
}

// ---------------- growth + mu (A read interleaved; asum built in LDS) ----------
__global__ __launch_bounds__(256) void growth_mu(const float* __restrict__ A,
                                                 float* __restrict__ ws,
                                                 const float* __restrict__ m_,
                                                 const float* __restrict__ s_,
                                                 const float* __restrict__ h_) {
    __shared__ float Ush[3][256];
    __shared__ float As[3][256];
    __shared__ float kinv[4];
    int b = blockIdx.x;
    int c = b >> 8;
    int x = b & 255;
    int t = threadIdx.x, wid = t >> 6, lane = t & 63;
    int nk = (c == 0) ? 4 : 3;
    if (wid < nk) {
        int k = (wid == 3) ? 9 : c*3 + wid;
        const float* rw = ws + OROWS + k*256;
        float v = rw[lane] + rw[64+lane] + rw[128+lane] + rw[192+lane];
        #pragma unroll
        for (int off = 32; off; off >>= 1) v += __shfl_xor(v, off);
        if (lane == 0) kinv[wid] = 1.0f / v;
    }
    #pragma unroll
    for (int rr = 0; rr < 3; ++rr) {
        int xr = x - 1 + rr;
        float sv = 0.0f;
        if (xr >= 0 && xr <= 255) {
            int base = (xr*256 + t)*3;
            sv = A[base] + A[base + 1] + A[base + 2];
        }
        As[rr][t] = sv;
    }
    __syncthreads();
    for (int rr = 0; rr < 3; ++rr) {
        int xr = x - 1 + rr;
        float outv = 0.0f;
        if (xr >= 0 && xr <= 255) {
            int idx = xr*256 + t;
            for (int kk = 0; kk < nk; ++kk) {
                int k = (kk == 3) ? 9 : c*3 + kk;
                float U = ws[OU(k) + idx] * kinv[kk];
                float z = (U - m_[k]) / s_[k];
                outv += h_[k] * (expf(-0.5f*z*z)*2.0f - 1.0f);
            }
        }
        Ush[rr][t] = outv;
    }
    __syncthreads();
    int y = t;
    float vA[3][3], vU[3][3];
    #pragma unroll
    for (int ii = 0; ii < 3; ++ii)
        #pragma unroll
        for (int jj = 0; jj < 3; ++jj) {
            int yy = y - 1 + jj;
            bool ok = (yy >= 0 && yy <= 255);
            vA[ii][jj] = ok ? As[ii][yy]  : 0.0f;
            vU[ii][jj] = ok ? Ush[ii][yy] : 0.0f;
        }
    float gyA = (vA[0][0] + 2.0f*vA[0][1] + vA[0][2]) - (vA[2][0] + 2.0f*vA[2][1] + vA[2][2]);
    float gxA = (vA[0][0] + 2.0f*vA[1][0] + vA[2][0]) - (vA[0][2] + 2.0f*vA[1][2] + vA[2][2]);
    float gy  = (vU[0][0] + 2.0f*vU[0][1] + vU[0][2]) - (vU[2][0] + 2.0f*vU[2][1] + vU[2][2]);
    float gx  = (vU[0][0] + 2.0f*vU[1][0] + vU[2][0]) - (vU[0][2] + 2.0f*vU[1][2] + vU[2][2]);
    float a = A[(x*256 + y)*3 + c];
    float al = (a / 3.0f); al = al * al;
    al = fminf(fmaxf(al, 0.0f), 1.0f);
    float F0 = gy * (1.0f - al) - gyA * al;
    float F1 = gx * (1.0f - al) - gxA * al;
    float d0 = fminf(fmaxf(0.2f * F0, -4.35f), 4.35f);
    float d1 = fminf(fmaxf(0.2f * F1, -4.35f), 4.35f);
    ws[OMUX(c) + x*256 + y] = fminf(fmaxf((float)x + 0.5f + d0, 0.65f), 255.35f);
    ws[OMUY(c) + x*256 + y] = fminf(fmaxf((float)y + 0.5f + d1, 0.65f), 255.35f);
}

// ---------------- reintegration (proven gather) ----------
__global__ __launch_bounds__(256) void rt_apply_v2(const float* __restrict__ A,
                                                   const float* __restrict__ ws,
                                                   float* __restrict__ out) {
    __shared__ float sA[11*256], sX[11*256], sY[11*256];
    int b = blockIdx.x;
    int c = b >> 8;
    int x = b & 255;
    const float* mx = ws + OMUX(c);
    const float* my = ws + OMUY(c);
    int t = threadIdx.x;
    #pragma unroll
    for (int i = 0; i < 11; ++i) {
        int src = (((x - (i - 5)) & 255) << 8) + t;
        sA[i*256 + t] = A[src*3 + c];
        sX[i*256 + t] = mx[src];
        sY[i*256 + t] = my[src];
    }
    __syncthreads();
    int y = t;
    float px = (float)x + 0.5f, py = (float)y + 0.5f;
    float acc = 0.0f;
    #pragma unroll
    for (int dx = -5; dx <= 5; ++dx) {
        int rb = (dx + 5) * 256;
        for (int dy = -5; dy <= 5; ++dy) {
            int sy = (y - dy) & 255;
            float a  = sA[rb + sy];
            float ax = 1.15f - fabsf(px - sX[rb + sy]);
            float ay = 1.15f - fabsf(py - sY[rb + sy]);
            ax = fminf(fmaxf(ax, 0.0f), 1.0f);
            ay = fminf(fmaxf(ay, 0.0f), 1.0f);
            acc = fmaf(a, ax * ay, acc);
        }
    }
    out[(x*256 + y)*3 + c] = acc * (1.0f / (4.0f * 0.65f * 0.65f));
}

extern "C" void kernel_launch(void* const* d_in, const int* in_sizes, int n_in,
                              void* d_out, int out_size, void* d_ws, size_t ws_size,
                              hipStream_t stream) {
    const float* A = (const float*)d_in[0];
    const float* R = (const float*)d_in[1];
    const float* r = (const float*)d_in[2];
    const float* m = (const float*)d_in[3];
    const float* s = (const float*)d_in[4];
    const float* h = (const float*)d_in[5];
    const float* a = (const float*)d_in[6];
    const float* b = (const float*)d_in[7];
    const float* w = (const float*)d_in[8];
    float* ws  = (float*)d_ws;
    float* out = (float*)d_out;

    fwd_rows<<<7*64, 256, 0, stream>>>(A, R, r, a, b, w, ws);
    fwd_cols<<<99 + 165, 256, 0, stream>>>(ws);
    inv_rows<<<5*64, 256, 0, stream>>>(ws);
    inv_cols<<<5*64, 256, 0, stream>>>(ws);
    growth_mu<<<768, 256, 0, stream>>>(A, ws, m, s, h);
    rt_apply_v2<<<768, 256, 0, stream>>>(A, ws, out);
}